// Round 1
// baseline (432.340 us; speedup 1.0000x reference)
//
#include <hip/hip_runtime.h>

// ---------------------------------------------------------------------------
// DualAttention on MI355X.  B=8 L=8 C=64 W=32 (WH=1024, LWH=8192) NH=128 FS=5
// All matmuls via v_mfma_f32_16x16x32_bf16.  fp32 accumulate everywhere.
// Spatial softmax: no max-subtraction (logits ~N(0,64), max ~48 nats < 88).
// Channel softmax: explicit max; QK uses hi/lo split bf16 (logits sigma=32).
// Workspace need ~49.4 MiB.
// ---------------------------------------------------------------------------

#define LOG2E 1.44269504088896340736f

typedef __attribute__((ext_vector_type(8))) short short8;   // bf16 x8 (A/B frag)
typedef __attribute__((ext_vector_type(4))) float f4;       // fp32 x4 (C/D frag)

#define MFMA16(a, b, c) __builtin_amdgcn_mfma_f32_16x16x32_bf16(a, b, c, 0, 0, 0)

__device__ __forceinline__ unsigned short f2bf(float f) {   // RNE float->bf16
  union { float f; unsigned u; } v; v.f = f;
  unsigned r = v.u + 0x7FFFu + ((v.u >> 16) & 1u);
  return (unsigned short)(r >> 16);
}
__device__ __forceinline__ float bf2f(unsigned short h) {
  union { unsigned u; float f; } v; v.u = ((unsigned)h) << 16;
  return v.f;
}
__device__ __forceinline__ float exp2fast(float x) {
#if __has_builtin(__builtin_amdgcn_exp2f)
  return __builtin_amdgcn_exp2f(x);
#else
  return exp2f(x);
#endif
}

// ---------------- workspace layout (bytes) ----------------
#define O_STATS 0ul                       // [2][8][2] f32 sum/sumsq (memset 0)
#define O_W1T   256ul                     // [2][25][64][64] bf16  conv1 weights
#define O_W2B   (O_W1T + 409600ul)        // [2][128][64] bf16     conv2 weights
#define O_LNW   (O_W2B + 32768ul)         // [2][1024][64] bf16    lnw transposed
#define O_LNB   (O_LNW + 262144ul)        // [2][1024][64] bf16
#define O_QSP   (O_LNB + 262144ul)        // [8][1024][64] bf16  q^T * log2e
#define O_QT    (O_QSP + 1048576ul)       // [8][1024][64] bf16  q^T (residual)
#define O_KSP   (O_QT  + 1048576ul)       // [8][8192][64] bf16  spatial K
#define O_VT    (O_KSP + 8388608ul)       // [8][64][8192] bf16  spatial V^T
#define O_VCT   (O_VT  + 8388608ul)       // [8][1024][512] bf16 channel V^T
#define O_KCH   (O_VCT + 8388608ul)       // [8][512][1024] bf16 channel K hi
#define O_KCL   (O_KCH + 8388608ul)       // [8][512][1024] bf16 channel K lo
#define O_QCH   (O_KCL + 8388608ul)       // [8][64][1024] bf16  channel q hi (*log2e)
#define O_QCL   (O_QCH + 1048576ul)       // [8][64][1024] bf16  channel q lo
#define O_PCH   (O_QCL + 1048576ul)       // [8][64][512] bf16   channel softmax
#define O_XS    (O_PCH + 524288ul)        // [8][1024][64] bf16  stem input (spatial)
#define O_XC    (O_XS  + 1048576ul)       // [8][1024][64] bf16  stem input (channel)
#define O_YT    (O_XC  + 1048576ul)       // [2][8][1024][64] bf16 conv1 out
// total = O_YT + 2097152 = 51,822,592 bytes (~49.4 MiB)

// ---------------- prep segment sizes ----------------
#define NSEG_A 204800u
#define NSEG_B 16384u
#define NSEG_C 131072u
#define NSEG_D 131072u
#define NSEG_E 524288u
#define NSEG_F 4194304u
#define NSEG_G 4194304u
#define NSEG_H 4194304u
#define NSEG_I 4194304u
#define NSEG_J 524288u
// total 18,309,120 threads = 71,520 blocks * 256

__global__ __launch_bounds__(256) void prep_kernel(
    const float* __restrict__ q, const float* __restrict__ keys,
    const float* __restrict__ values,
    const float* __restrict__ sw1, const float* __restrict__ slnw,
    const float* __restrict__ slnb, const float* __restrict__ sw2,
    const float* __restrict__ cw1, const float* __restrict__ clnw,
    const float* __restrict__ clnb, const float* __restrict__ cw2,
    char* __restrict__ ws)
{
  unsigned i = blockIdx.x * 256u + threadIdx.x;
  if (i < NSEG_A) {                       // W1t[s][off][co][ci] <- w1[co][ci][off]
    unsigned ci = i & 63u, co = (i >> 6) & 63u, t = i >> 12;
    unsigned off = t % 25u, st = t / 25u;
    const float* w = st ? cw1 : sw1;
    ((unsigned short*)(ws + O_W1T))[i] = f2bf(w[(co * 64u + ci) * 25u + off]);
    return;
  }
  i -= NSEG_A;
  if (i < NSEG_B) {                       // W2b[s][nh][c]
    unsigned c = i & 63u, nh = (i >> 6) & 127u, st = i >> 13;
    const float* w = st ? cw2 : sw2;
    ((unsigned short*)(ws + O_W2B))[i] = f2bf(w[nh * 64u + c]);
    return;
  }
  i -= NSEG_B;
  if (i < NSEG_C) {                       // LnwT[s][p][c] <- lnw[c][p]
    unsigned c = i & 63u, p = (i >> 6) & 1023u, st = i >> 16;
    const float* w = st ? clnw : slnw;
    ((unsigned short*)(ws + O_LNW))[i] = f2bf(w[c * 1024u + p]);
    return;
  }
  i -= NSEG_C;
  if (i < NSEG_D) {                       // LnbT
    unsigned c = i & 63u, p = (i >> 6) & 1023u, st = i >> 16;
    const float* w = st ? clnb : slnb;
    ((unsigned short*)(ws + O_LNB))[i] = f2bf(w[c * 1024u + p]);
    return;
  }
  i -= NSEG_D;
  if (i < NSEG_E) {                       // Qsp (scaled) + Qt <- q[b][c][p]
    unsigned c = i & 63u, p = (i >> 6) & 1023u, b = i >> 16;
    float v = q[(b * 64u + c) * 1024u + p];
    ((unsigned short*)(ws + O_QT))[i]  = f2bf(v);
    ((unsigned short*)(ws + O_QSP))[i] = f2bf(v * LOG2E);
    return;
  }
  i -= NSEG_E;
  if (i < NSEG_F) {                       // Ksp[b][m][c] <- keys[b][l][c][p]
    unsigned c = i & 63u, m = (i >> 6) & 8191u, b = i >> 19;
    unsigned l = m >> 10, pp = m & 1023u;
    ((unsigned short*)(ws + O_KSP))[i] = f2bf(keys[((b * 8u + l) * 64u + c) * 1024u + pp]);
    return;
  }
  i -= NSEG_F;
  if (i < NSEG_G) {                       // Vt[b][c][m] <- values[b][l][c][p]
    unsigned m = i & 8191u, c = (i >> 13) & 63u, b = i >> 19;
    unsigned l = m >> 10, pp = m & 1023u;
    ((unsigned short*)(ws + O_VT))[i] = f2bf(values[((b * 8u + l) * 64u + c) * 1024u + pp]);
    return;
  }
  i -= NSEG_G;
  if (i < NSEG_H) {                       // Vct[b][p][mc] <- values[b][mc][p]
    unsigned mc = i & 511u, p = (i >> 9) & 1023u, b = i >> 19;
    ((unsigned short*)(ws + O_VCT))[i] = f2bf(values[(b * 512u + mc) * 1024u + p]);
    return;
  }
  i -= NSEG_H;
  if (i < NSEG_I) {                       // channel K hi/lo split (identity layout)
    float v = keys[i];
    unsigned short h = f2bf(v);
    ((unsigned short*)(ws + O_KCH))[i] = h;
    ((unsigned short*)(ws + O_KCL))[i] = f2bf(v - bf2f(h));
    return;
  }
  i -= NSEG_I;
  if (i < NSEG_J) {                       // channel q hi/lo split, *log2e
    float v = q[i] * LOG2E;
    unsigned short h = f2bf(v);
    ((unsigned short*)(ws + O_QCH))[i] = h;
    ((unsigned short*)(ws + O_QCL))[i] = f2bf(v - bf2f(h));
  }
}

// ---------------- spatial attention (flash, no-max softmax) ----------------
// grid: 256 blocks = (b:8) x (qtile:32 of 32 rows); 256 threads = 4 waves.
// Each wave handles kv rows [it*256 + w*64, +64).  Per iter:
//   S[32q x 64kv] = Qs @ Ksp^T (MFMA) -> exp2 -> P to LDS (bf16) -> O += P @ V.
__global__ __launch_bounds__(256) void spat_attn(char* __restrict__ ws)
{
  const unsigned short* Qs = (const unsigned short*)(ws + O_QSP);
  const unsigned short* Ks = (const unsigned short*)(ws + O_KSP);
  const unsigned short* Vt = (const unsigned short*)(ws + O_VT);
  const unsigned short* Qt = (const unsigned short*)(ws + O_QT);
  unsigned short* Xs = (unsigned short*)(ws + O_XS);

  const int b = blockIdx.x >> 5;
  const int qt = blockIdx.x & 31;
  const int w = threadIdx.x >> 6;
  const int lane = threadIdx.x & 63;
  const int low4 = lane & 15, quad = lane >> 4;

  __shared__ __align__(16) unsigned short Plds[4][32][72];  // stride 72: avoid b128-read conflicts
  __shared__ float Ored[4][32][64];
  __shared__ float Dred[4][32];

  const unsigned short* Qb = Qs + ((size_t)(b * 1024 + qt * 32)) * 64;
  short8 qa[2][2];
#pragma unroll
  for (int m = 0; m < 2; ++m)
#pragma unroll
    for (int ks = 0; ks < 2; ++ks)
      qa[m][ks] = *(const short8*)(Qb + (m * 16 + low4) * 64 + ks * 32 + quad * 8);

  f4 accO[2][4];
  float den[2][4];
#pragma unroll
  for (int m = 0; m < 2; ++m)
#pragma unroll
    for (int n = 0; n < 4; ++n) {
      accO[m][n] = (f4){0.f, 0.f, 0.f, 0.f};
      den[m][n] = 0.f;
    }

  const unsigned short* Kb = Ks + (size_t)b * 8192 * 64;
  const unsigned short* Vb = Vt + (size_t)b * 64 * 8192;

  for (int it = 0; it < 32; ++it) {
    const int kv0 = it * 256 + w * 64;
    f4 s[2][4];
#pragma unroll
    for (int m = 0; m < 2; ++m)
#pragma unroll
      for (int n = 0; n < 4; ++n) s[m][n] = (f4){0.f, 0.f, 0.f, 0.f};

#pragma unroll
    for (int ks = 0; ks < 2; ++ks)
#pragma unroll
      for (int n = 0; n < 4; ++n) {
        short8 kb = *(const short8*)(Kb + (size_t)(kv0 + n * 16 + low4) * 64 + ks * 32 + quad * 8);
        s[0][n] = MFMA16(qa[0][ks], kb, s[0][n]);
        s[1][n] = MFMA16(qa[1][ks], kb, s[1][n]);
      }
    // exp2 (logits already in log2 units), accumulate denominator, stash P
#pragma unroll
    for (int m = 0; m < 2; ++m)
#pragma unroll
      for (int n = 0; n < 4; ++n)
#pragma unroll
        for (int r = 0; r < 4; ++r) {
          float e = exp2fast(s[m][n][r]);
          den[m][r] += e;
          Plds[w][m * 16 + quad * 4 + r][n * 16 + low4] = f2bf(e);
        }
    // O += P @ V  (P via LDS round-trip: C-layout -> A-layout)
#pragma unroll
    for (int ks = 0; ks < 2; ++ks) {
      short8 pa0 = *(const short8*)&Plds[w][low4][ks * 32 + quad * 8];
      short8 pa1 = *(const short8*)&Plds[w][16 + low4][ks * 32 + quad * 8];
#pragma unroll
      for (int n = 0; n < 4; ++n) {
        short8 vb = *(const short8*)(Vb + (size_t)(n * 16 + low4) * 8192 + kv0 + ks * 32 + quad * 8);
        accO[0][n] = MFMA16(pa0, vb, accO[0][n]);
        accO[1][n] = MFMA16(pa1, vb, accO[1][n]);
      }
    }
  }

  // cross-wave reduce of (num, den), divide, add residual, store bf16 [p][c]
#pragma unroll
  for (int m = 0; m < 2; ++m)
#pragma unroll
    for (int r = 0; r < 4; ++r)
#pragma unroll
      for (int o = 1; o < 16; o <<= 1) den[m][r] += __shfl_xor(den[m][r], o, 64);

#pragma unroll
  for (int m = 0; m < 2; ++m)
#pragma unroll
    for (int n = 0; n < 4; ++n)
#pragma unroll
      for (int r = 0; r < 4; ++r)
        Ored[w][m * 16 + quad * 4 + r][n * 16 + low4] = accO[m][n][r];
  if (low4 == 0) {
#pragma unroll
    for (int m = 0; m < 2; ++m)
#pragma unroll
      for (int r = 0; r < 4; ++r) Dred[w][m * 16 + quad * 4 + r] = den[m][r];
  }
  __syncthreads();

  const int t = threadIdx.x;
  const int qrow = t >> 3, c0 = (t & 7) * 8;
  float dtot = Dred[0][qrow] + Dred[1][qrow] + Dred[2][qrow] + Dred[3][qrow];
  float rdt = 1.0f / dtot;
  size_t obase = ((size_t)(b * 1024 + qt * 32 + qrow)) * 64 + c0;
  short8 qv = *(const short8*)(Qt + obase);
  short8 out8;
#pragma unroll
  for (int j = 0; j < 8; ++j) {
    float num = Ored[0][qrow][c0 + j] + Ored[1][qrow][c0 + j] +
                Ored[2][qrow][c0 + j] + Ored[3][qrow][c0 + j];
    out8[j] = (short)f2bf(num * rdt + bf2f((unsigned short)qv[j]));
  }
  *(short8*)(Xs + obase) = out8;
}

// ---------------- channel attention: S + softmax -> P ----------------
// grid: 32 blocks = (b:8) x (ctile:4 of 16 rows).  Split-bf16 QK (3 MFMAs).
__global__ __launch_bounds__(256) void chan_A(char* __restrict__ ws)
{
  const unsigned short* qh = (const unsigned short*)(ws + O_QCH);
  const unsigned short* ql = (const unsigned short*)(ws + O_QCL);
  const unsigned short* kh = (const unsigned short*)(ws + O_KCH);
  const unsigned short* kl = (const unsigned short*)(ws + O_KCL);
  unsigned short* P = (unsigned short*)(ws + O_PCH);

  const int b = blockIdx.x >> 2, ct = blockIdx.x & 3;
  const int w = threadIdx.x >> 6, lane = threadIdx.x & 63;
  const int low4 = lane & 15, quad = lane >> 4;

  __shared__ float S[16][512];

  f4 s[8];
#pragma unroll
  for (int n = 0; n < 8; ++n) s[n] = (f4){0.f, 0.f, 0.f, 0.f};

  const unsigned short* qhb = qh + ((size_t)(b * 64 + ct * 16)) * 1024;
  const unsigned short* qlb = ql + ((size_t)(b * 64 + ct * 16)) * 1024;

  for (int ks = 0; ks < 32; ++ks) {
    short8 ah = *(const short8*)(qhb + low4 * 1024 + ks * 32 + quad * 8);
    short8 al = *(const short8*)(qlb + low4 * 1024 + ks * 32 + quad * 8);
#pragma unroll
    for (int n = 0; n < 8; ++n) {
      size_t ko = ((size_t)(b * 512 + w * 128 + n * 16 + low4)) * 1024 + ks * 32 + quad * 8;
      short8 bh = *(const short8*)(kh + ko);
      short8 bl = *(const short8*)(kl + ko);
      s[n] = MFMA16(ah, bh, s[n]);
      s[n] = MFMA16(al, bh, s[n]);
      s[n] = MFMA16(ah, bl, s[n]);
    }
  }
#pragma unroll
  for (int n = 0; n < 8; ++n)
#pragma unroll
    for (int r = 0; r < 4; ++r)
      S[quad * 4 + r][w * 128 + n * 16 + low4] = s[n][r];
  __syncthreads();

  // row softmax (logits in log2 units): 16 threads per row
  const int row = threadIdx.x >> 4, tc = threadIdx.x & 15;
  float mx = -1e30f;
  for (int j = tc; j < 512; j += 16) mx = fmaxf(mx, S[row][j]);
#pragma unroll
  for (int o = 1; o < 16; o <<= 1) mx = fmaxf(mx, __shfl_xor(mx, o, 64));
  float sum = 0.f;
  for (int j = tc; j < 512; j += 16) {
    float e = exp2fast(S[row][j] - mx);
    S[row][j] = e;
    sum += e;
  }
#pragma unroll
  for (int o = 1; o < 16; o <<= 1) sum += __shfl_xor(sum, o, 64);
  float rs = 1.0f / sum;
  for (int j = tc; j < 512; j += 16)
    P[((size_t)(b * 64 + ct * 16 + row)) * 512 + j] = f2bf(S[row][j] * rs);
}

// ---------------- channel attention: O = P @ Vc, + residual ----------------
// grid: 64 blocks = (b:8) x (ptile:8 of 128 px)
__global__ __launch_bounds__(256) void chan_B(char* __restrict__ ws)
{
  const unsigned short* P = (const unsigned short*)(ws + O_PCH);
  const unsigned short* Vct = (const unsigned short*)(ws + O_VCT);
  const unsigned short* Qt = (const unsigned short*)(ws + O_QT);
  unsigned short* Xc = (unsigned short*)(ws + O_XC);

  const int b = blockIdx.x >> 3, pt = blockIdx.x & 7;
  const int w = threadIdx.x >> 6, lane = threadIdx.x & 63;
  const int low4 = lane & 15, quad = lane >> 4;

  f4 acc[4][2];
#pragma unroll
  for (int m = 0; m < 4; ++m)
#pragma unroll
    for (int n = 0; n < 2; ++n) acc[m][n] = (f4){0.f, 0.f, 0.f, 0.f};

  for (int ks = 0; ks < 16; ++ks) {
    short8 a[4];
#pragma unroll
    for (int m = 0; m < 4; ++m)
      a[m] = *(const short8*)(P + ((size_t)(b * 64 + m * 16 + low4)) * 512 + ks * 32 + quad * 8);
#pragma unroll
    for (int n = 0; n < 2; ++n) {
      int p = pt * 128 + w * 32 + n * 16 + low4;
      short8 vb = *(const short8*)(Vct + ((size_t)(b * 1024 + p)) * 512 + ks * 32 + quad * 8);
#pragma unroll
      for (int m = 0; m < 4; ++m) acc[m][n] = MFMA16(a[m], vb, acc[m][n]);
    }
  }
#pragma unroll
  for (int m = 0; m < 4; ++m)
#pragma unroll
    for (int n = 0; n < 2; ++n)
#pragma unroll
      for (int r = 0; r < 4; ++r) {
        int c = m * 16 + quad * 4 + r;
        int p = pt * 128 + w * 32 + n * 16 + low4;
        size_t o = ((size_t)(b * 1024 + p)) * 64 + c;
        Xc[o] = f2bf(acc[m][n][r] + bf2f(Qt[o]));
      }
}

// ---------------- conv 5x5 (both stems) + bias + LN stats ----------------
// grid: 256 blocks = (stem:2) x (b:8) x (ptile:16 of 64 px).
// y^T[co][px] = sum_off W1t[off] @ Xshift[off];  25-offset implicit GEMM.
__global__ __launch_bounds__(256) void conv5(char* __restrict__ ws,
                                             const float* __restrict__ sb1,
                                             const float* __restrict__ cb1)
{
  const int id = blockIdx.x;
  const int s = id >> 7, b = (id >> 4) & 7, pt = id & 15;
  const int w = threadIdx.x >> 6, lane = threadIdx.x & 63;
  const int low4 = lane & 15, quad = lane >> 4;

  const unsigned short* X = (const unsigned short*)(ws + (s ? O_XC : O_XS));
  const unsigned short* W1t = (const unsigned short*)(ws + O_W1T);
  unsigned short* Yt = (unsigned short*)(ws + O_YT);
  float* stats = (float*)(ws + O_STATS);
  const float* b1p = s ? cb1 : sb1;

  const int px0 = pt * 64 + w * 16;
  const int p = px0 + low4;
  const int y0 = p >> 5, x0 = p & 31;

  f4 acc[4];
#pragma unroll
  for (int m = 0; m < 4; ++m) acc[m] = (f4){0.f, 0.f, 0.f, 0.f};

  for (int off = 0; off < 25; ++off) {
    const int dy = off / 5 - 2, dx = off % 5 - 2;
    const int ys = y0 + dy, xs = x0 + dx;
    const bool valid = ((unsigned)ys < 32u) & ((unsigned)xs < 32u);
    const int psrc = valid ? (p + dy * 32 + dx) : p;   // clamped: load stays in-bounds
    const unsigned short* xp = X + ((size_t)(b * 1024 + psrc)) * 64;
    const unsigned short* wp = W1t + ((size_t)((s * 25 + off) * 64)) * 64;
#pragma unroll
    for (int ks = 0; ks < 2; ++ks) {
      short8 bv = *(const short8*)(xp + ks * 32 + quad * 8);
      if (!valid) bv = (short8)0;
#pragma unroll
      for (int m = 0; m < 4; ++m) {
        short8 av = *(const short8*)(wp + (m * 16 + low4) * 64 + ks * 32 + quad * 8);
        acc[m] = MFMA16(av, bv, acc[m]);
      }
    }
  }

  float ls = 0.f, ls2 = 0.f;
#pragma unroll
  for (int m = 0; m < 4; ++m)
#pragma unroll
    for (int r = 0; r < 4; ++r) {
      int co = m * 16 + quad * 4 + r;
      float y = acc[m][r] + b1p[co];
      Yt[((size_t)((s * 8 + b) * 1024 + p)) * 64 + co] = f2bf(y);
      ls += y;
      ls2 += y * y;
    }
#pragma unroll
  for (int o = 1; o < 64; o <<= 1) {
    ls += __shfl_xor(ls, o, 64);
    ls2 += __shfl_xor(ls2, o, 64);
  }
  __shared__ float red[2][4];
  if (lane == 0) { red[0][w] = ls; red[1][w] = ls2; }
  __syncthreads();
  if (threadIdx.x == 0) {
    float a = red[0][0] + red[0][1] + red[0][2] + red[0][3];
    float a2 = red[1][0] + red[1][1] + red[1][2] + red[1][3];
    atomicAdd(&stats[(s * 8 + b) * 2 + 0], a);
    atomicAdd(&stats[(s * 8 + b) * 2 + 1], a2);
  }
}

// ---------------- LN + ReLU + 1x1 conv epilogue ----------------
// grid: 128 blocks = (stem:2) x (b:8) x (ptile:8 of 128 px)
__global__ __launch_bounds__(256) void finalk(char* __restrict__ ws,
                                              const float* __restrict__ sb2,
                                              const float* __restrict__ cb2,
                                              float* __restrict__ out)
{
  const int id = blockIdx.x;
  const int s = id >> 6, b = (id >> 3) & 7, pt = id & 7;
  const int w = threadIdx.x >> 6, lane = threadIdx.x & 63;
  const int low4 = lane & 15, quad = lane >> 4;

  const unsigned short* Yt = (const unsigned short*)(ws + O_YT);
  const unsigned short* LnwT = (const unsigned short*)(ws + O_LNW);
  const unsigned short* LnbT = (const unsigned short*)(ws + O_LNB);
  const unsigned short* W2b = (const unsigned short*)(ws + O_W2B);
  const float* stats = (const float*)(ws + O_STATS);
  const float* b2p = s ? cb2 : sb2;

  const float inv = 1.0f / 65536.0f;
  const float mu = stats[(s * 8 + b) * 2 + 0] * inv;
  const float ms = stats[(s * 8 + b) * 2 + 1] * inv;
  const float rsig = rsqrtf(ms - mu * mu + 1e-5f);

  f4 acc[8][2];
#pragma unroll
  for (int m = 0; m < 8; ++m)
#pragma unroll
    for (int n = 0; n < 2; ++n) acc[m][n] = (f4){0.f, 0.f, 0.f, 0.f};

#pragma unroll
  for (int ks = 0; ks < 2; ++ks) {
    short8 a[8];
#pragma unroll
    for (int m = 0; m < 8; ++m)
      a[m] = *(const short8*)(W2b + ((size_t)(s * 128 + m * 16 + low4)) * 64 + ks * 32 + quad * 8);
#pragma unroll
    for (int n = 0; n < 2; ++n) {
      const int p2 = pt * 128 + w * 32 + n * 16 + low4;
      size_t yo = ((size_t)((s * 8 + b) * 1024 + p2)) * 64 + ks * 32 + quad * 8;
      size_t lo = ((size_t)(s * 1024 + p2)) * 64 + ks * 32 + quad * 8;
      short8 yv = *(const short8*)(Yt + yo);
      short8 lwv = *(const short8*)(LnwT + lo);
      short8 lbv = *(const short8*)(LnbT + lo);
      short8 zv;
#pragma unroll
      for (int j = 0; j < 8; ++j) {
        float z = (bf2f((unsigned short)yv[j]) - mu) * rsig * bf2f((unsigned short)lwv[j]) +
                  bf2f((unsigned short)lbv[j]);
        zv[j] = (short)f2bf(fmaxf(z, 0.f));
      }
#pragma unroll
      for (int m = 0; m < 8; ++m) acc[m][n] = MFMA16(a[m], zv, acc[m][n]);
    }
  }
#pragma unroll
  for (int m = 0; m < 8; ++m)
#pragma unroll
    for (int n = 0; n < 2; ++n)
#pragma unroll
      for (int r = 0; r < 4; ++r) {
        int nh = m * 16 + quad * 4 + r;
        int p2 = pt * 128 + w * 32 + n * 16 + low4;
        out[((size_t)((s * 8 + b) * 128 + nh)) * 1024 + p2] = acc[m][n][r] + b2p[nh];
      }
}

extern "C" void kernel_launch(void* const* d_in, const int* in_sizes, int n_in,
                              void* d_out, int out_size, void* d_ws, size_t ws_size,
                              hipStream_t stream)
{
  const float* q    = (const float*)d_in[0];
  const float* keys = (const float*)d_in[1];
  const float* vals = (const float*)d_in[2];
  const float* sw1  = (const float*)d_in[3];
  const float* sb1  = (const float*)d_in[4];
  const float* slnw = (const float*)d_in[5];
  const float* slnb = (const float*)d_in[6];
  const float* sw2  = (const float*)d_in[7];
  const float* sb2  = (const float*)d_in[8];
  const float* cw1  = (const float*)d_in[9];
  const float* cb1  = (const float*)d_in[10];
  const float* clnw = (const float*)d_in[11];
  const float* clnb = (const float*)d_in[12];
  const float* cw2  = (const float*)d_in[13];
  const float* cb2  = (const float*)d_in[14];
  char* ws = (char*)d_ws;

  hipMemsetAsync(ws + O_STATS, 0, 256, stream);
  prep_kernel<<<71520, 256, 0, stream>>>(q, keys, vals, sw1, slnw, slnb, sw2,
                                         cw1, clnw, clnb, cw2, ws);
  spat_attn<<<256, 256, 0, stream>>>(ws);
  chan_A<<<32, 256, 0, stream>>>(ws);
  chan_B<<<64, 256, 0, stream>>>(ws);
  conv5<<<256, 256, 0, stream>>>(ws, sb1, cb1);
  finalk<<<128, 256, 0, stream>>>(ws, sb2, cb2, (float*)d_out);
}

// Round 2
// 317.868 us; speedup vs baseline: 1.3601x; 1.3601x over previous
//
#include <hip/hip_runtime.h>

// ---------------------------------------------------------------------------
// DualAttention on MI355X.  B=8 L=8 C=64 W=32 (WH=1024, LWH=8192) NH=128 FS=5
// R2: occupancy-driven rewrite.
//  - spat_attn: 1024 blocks (KV split 2-way, 16 q-rows/block), partials + fin.
//  - prep: coalesced 64x64 LDS-tile transpose, reads inputs once.
//  - chan: two-stage S (k-split partials, no atomics) + softmax + PV.
//  - conv5: 8-wave blocks, 25 offsets split across wave-halves, LDS reduce.
// ---------------------------------------------------------------------------

#define LOG2E 1.44269504088896340736f

typedef __attribute__((ext_vector_type(8))) short short8;   // bf16 x8 frag
typedef __attribute__((ext_vector_type(4))) float f4;       // fp32 x4 frag

#define MFMA16(a, b, c) __builtin_amdgcn_mfma_f32_16x16x32_bf16(a, b, c, 0, 0, 0)

__device__ __forceinline__ unsigned short f2bf(float f) {   // RNE float->bf16
  union { float f; unsigned u; } v; v.f = f;
  unsigned r = v.u + 0x7FFFu + ((v.u >> 16) & 1u);
  return (unsigned short)(r >> 16);
}
__device__ __forceinline__ unsigned short f2bf_rz(float f) { // truncate (P only)
  union { float f; unsigned u; } v; v.f = f;
  return (unsigned short)(v.u >> 16);
}
__device__ __forceinline__ float bf2f(unsigned short h) {
  union { unsigned u; float f; } v; v.u = ((unsigned)h) << 16;
  return v.f;
}
__device__ __forceinline__ float exp2fast(float x) {
#if __has_builtin(__builtin_amdgcn_exp2f)
  return __builtin_amdgcn_exp2f(x);
#else
  return exp2f(x);
#endif
}

// ---------------- workspace layout (bytes), total 52,347,136 (~49.9MB) -----
#define O_STATS 0ul                      // [2][8][2] f32 (memset 0)
#define O_W1T   256ul                    // [2][25][64][64] bf16
#define O_W2B   409856ul                 // [2][128][64] bf16
#define O_QT    442624ul                 // [8][1024][64] bf16  q^T
#define O_KSP   1491200ul                // [8][8192][64] bf16  spatial K
#define O_VT    9879808ul                // [8][64][8192] bf16  spatial V^T
#define O_VCT   18268416ul               // [8][1024][512] bf16 channel V^T
#define O_KCH   26657024ul               // [8][512][1024] bf16 channel K hi
#define O_KCL   35045632ul               // [8][512][1024] bf16 channel K lo
#define O_PART  43434240ul               // 4.5MB overlay region:
#define O_NUM   O_PART                   //   [8][64][2][16][64] f32 (spat num)
#define O_DEN   (O_PART + 4194304ul)     //   [8][64][2][16] f32    (spat den)
#define O_SP    O_PART                   //   [4][8][64][512] f32 (chan S part)
#define O_PCH   (O_PART + 4194304ul)     //   [8][64][512] bf16   (chan P)
#define O_XS    48152832ul               // [8][1024][64] bf16 stem in (spatial)
#define O_XC    49201408ul               // [8][1024][64] bf16 stem in (channel)
#define O_YT    50249984ul               // [2][8][1024][64] bf16 conv1 out

// ---------------- prep: small weights (coalesced enough, tiny) -------------
__global__ __launch_bounds__(256) void prep_misc(
    const float* __restrict__ sw1, const float* __restrict__ sw2,
    const float* __restrict__ cw1, const float* __restrict__ cw2,
    char* __restrict__ ws)
{
  unsigned i = blockIdx.x * 256u + threadIdx.x;
  if (i < 204800u) {                     // W1t[s][off][co][ci] <- w1[co][ci][off]
    unsigned ci = i & 63u, co = (i >> 6) & 63u, t = i >> 12;
    unsigned off = t % 25u, st = t / 25u;
    const float* w = st ? cw1 : sw1;
    ((unsigned short*)(ws + O_W1T))[i] = f2bf(w[(co * 64u + ci) * 25u + off]);
    return;
  }
  i -= 204800u;
  if (i < 16384u) {                      // W2b[s][nh][c]
    unsigned c = i & 63u, nh = (i >> 6) & 127u, st = i >> 13;
    const float* w = st ? cw2 : sw2;
    ((unsigned short*)(ws + O_W2B))[i] = f2bf(w[nh * 64u + c]);
  }
}

// ---------------- prep: batched 64x64 tile transpose (coalesced) -----------
// jobs: [0,1024) keys (mat=b*8+l), [1024,2048) values, [2048,2176) q (mat=b).
// Reads a 64x64 f32 tile coalesced, emits identity-layout bf16 outputs from
// registers, and transposed bf16 outputs through LDS.
__global__ __launch_bounds__(256) void prep_tr(
    const float* __restrict__ q, const float* __restrict__ keys,
    const float* __restrict__ values, char* __restrict__ ws)
{
  __shared__ float T[64][65];
  unsigned short* KCH = (unsigned short*)(ws + O_KCH);
  unsigned short* KCL = (unsigned short*)(ws + O_KCL);
  unsigned short* VTp = (unsigned short*)(ws + O_VT);
  unsigned short* KSP = (unsigned short*)(ws + O_KSP);
  unsigned short* VCT = (unsigned short*)(ws + O_VCT);
  unsigned short* QT  = (unsigned short*)(ws + O_QT);

  const int job = blockIdx.x, t = threadIdx.x;
  int kind, mat;
  if (job < 1024)      { kind = 0; mat = job >> 4; }
  else if (job < 2048) { kind = 1; mat = (job - 1024) >> 4; }
  else                 { kind = 2; mat = (job - 2048) >> 4; }
  const int pt = job & 15, p0 = pt * 64;
  const float* src = (kind == 0 ? keys : kind == 1 ? values : q) + (size_t)mat * 65536;

  const int r0 = t >> 4, c4 = (t & 15) * 4;
#pragma unroll
  for (int pass = 0; pass < 4; ++pass) {
    const int r = pass * 16 + r0;
    float4 v = *(const float4*)(src + (size_t)r * 1024 + p0 + c4);
    float vv[4] = {v.x, v.y, v.z, v.w};
    T[r][c4] = vv[0]; T[r][c4 + 1] = vv[1]; T[r][c4 + 2] = vv[2]; T[r][c4 + 3] = vv[3];
    if (kind == 0) {                     // channel K hi/lo (identity layout)
      size_t gi = ((size_t)mat * 64 + r) * 1024 + p0 + c4;
      ushort4 h, l;
      unsigned short* hp = (unsigned short*)&h; unsigned short* lp = (unsigned short*)&l;
#pragma unroll
      for (int j = 0; j < 4; ++j) {
        unsigned short hi = f2bf(vv[j]);
        hp[j] = hi; lp[j] = f2bf(vv[j] - bf2f(hi));
      }
      *(ushort4*)(KCH + gi) = h;
      *(ushort4*)(KCL + gi) = l;
    } else if (kind == 1) {              // spatial V^T[b][c][l*1024+p]
      int b = mat >> 3, l = mat & 7;
      size_t gi = ((size_t)b * 64 + r) * 8192 + l * 1024 + p0 + c4;
      ushort4 o; unsigned short* op = (unsigned short*)&o;
#pragma unroll
      for (int j = 0; j < 4; ++j) op[j] = f2bf(vv[j]);
      *(ushort4*)(VTp + gi) = o;
    }
  }
  __syncthreads();
  // transposed writes: dest row = src col p, dest cols = src rows (channels)
#pragma unroll
  for (int pass = 0; pass < 2; ++pass) {
    const int p = pass * 32 + (t >> 3), cs = (t & 7) * 8;
    short8 o;
#pragma unroll
    for (int j = 0; j < 8; ++j) o[j] = (short)f2bf(T[cs + j][p]);
    if (kind == 0) {                     // Ksp[b][l*1024+p][c]
      int b = mat >> 3, l = mat & 7;
      *(short8*)(KSP + ((size_t)b * 8192 + l * 1024 + p0 + p) * 64 + cs) = o;
    } else if (kind == 1) {              // Vct[b][p][l*64+c]
      int b = mat >> 3, l = mat & 7;
      *(short8*)(VCT + ((size_t)b * 1024 + p0 + p) * 512 + l * 64 + cs) = o;
    } else {                             // Qt[b][p][c]
      *(short8*)(QT + ((size_t)mat * 1024 + p0 + p) * 64 + cs) = o;
    }
  }
}

// ---------------- spatial attention (flash, no-max, KV-split partials) -----
// grid 1024 = (b:8) x (qt:64 of 16 rows) x (s:2 KV halves); 4 waves/block.
// Wave w sweeps kv [s*4096 + it*256 + w*64) for it in [0,16).
__global__ __launch_bounds__(256) void spat_attn(char* __restrict__ ws)
{
  const unsigned short* QT = (const unsigned short*)(ws + O_QT);
  const unsigned short* Ks = (const unsigned short*)(ws + O_KSP);
  const unsigned short* Vt = (const unsigned short*)(ws + O_VT);
  float* NUM = (float*)(ws + O_NUM);
  float* DEN = (float*)(ws + O_DEN);

  const int b = blockIdx.x >> 7;
  const int qt = (blockIdx.x >> 1) & 63;
  const int s = blockIdx.x & 1;
  const int w = threadIdx.x >> 6, lane = threadIdx.x & 63;
  const int low4 = lane & 15, quad = lane >> 4;

  __shared__ __align__(16) float Osum[4][16][64];          // 16KB
  __shared__ float Dsum[4][16];
  unsigned short (*Plds)[16][72] =
      reinterpret_cast<unsigned short(*)[16][72]>(&Osum[0][0][0]);  // 9.2KB alias

  // Q fragment (rows qt*16+low4), scaled by log2e on the fly
  const unsigned short* Qb = QT + ((size_t)(b * 1024 + qt * 16)) * 64;
  short8 qa[2];
#pragma unroll
  for (int ks = 0; ks < 2; ++ks) {
    short8 qr = *(const short8*)(Qb + low4 * 64 + ks * 32 + quad * 8);
    short8 qs;
#pragma unroll
    for (int j = 0; j < 8; ++j) qs[j] = (short)f2bf(bf2f((unsigned short)qr[j]) * LOG2E);
    qa[ks] = qs;
  }

  f4 accO[4];
  float den[4];
#pragma unroll
  for (int n = 0; n < 4; ++n) accO[n] = (f4){0.f, 0.f, 0.f, 0.f};
#pragma unroll
  for (int r = 0; r < 4; ++r) den[r] = 0.f;

  const unsigned short* Kb = Ks + (size_t)b * 8192 * 64;
  const unsigned short* Vb = Vt + (size_t)b * 64 * 8192;

  for (int it = 0; it < 16; ++it) {
    const int kv0 = s * 4096 + it * 256 + w * 64;
    f4 sS[4];
#pragma unroll
    for (int n = 0; n < 4; ++n) sS[n] = (f4){0.f, 0.f, 0.f, 0.f};
#pragma unroll
    for (int ks = 0; ks < 2; ++ks)
#pragma unroll
      for (int n = 0; n < 4; ++n) {
        short8 kb = *(const short8*)(Kb + (size_t)(kv0 + n * 16 + low4) * 64 + ks * 32 + quad * 8);
        sS[n] = MFMA16(qa[ks], kb, sS[n]);
      }
#pragma unroll
    for (int n = 0; n < 4; ++n)
#pragma unroll
      for (int r = 0; r < 4; ++r) {
        float e = exp2fast(sS[n][r]);
        den[r] += e;
        Plds[w][quad * 4 + r][n * 16 + low4] = f2bf_rz(e);
      }
#pragma unroll
    for (int ks = 0; ks < 2; ++ks) {
      short8 pa = *(const short8*)&Plds[w][low4][ks * 32 + quad * 8];
#pragma unroll
      for (int n = 0; n < 4; ++n) {
        short8 vb = *(const short8*)(Vb + (size_t)(n * 16 + low4) * 8192 + kv0 + ks * 32 + quad * 8);
        accO[n] = MFMA16(pa, vb, accO[n]);
      }
    }
  }

  // den: reduce over the 16 low4 lanes within each quad group
#pragma unroll
  for (int r = 0; r < 4; ++r)
#pragma unroll
    for (int o = 1; o < 16; o <<= 1) den[r] += __shfl_xor(den[r], o, 64);

  __syncthreads();                       // all waves done with Plds (aliased)
#pragma unroll
  for (int n = 0; n < 4; ++n)
#pragma unroll
    for (int r = 0; r < 4; ++r)
      Osum[w][quad * 4 + r][n * 16 + low4] = accO[n][r];
  if (low4 == 0) {
#pragma unroll
    for (int r = 0; r < 4; ++r) Dsum[w][quad * 4 + r] = den[r];
  }
  __syncthreads();

  const int t = threadIdx.x;
  if (t < 128) {
    const int qrow = t >> 3, c0 = (t & 7) * 8;
    float n8[8];
#pragma unroll
    for (int j = 0; j < 8; ++j)
      n8[j] = Osum[0][qrow][c0 + j] + Osum[1][qrow][c0 + j] +
              Osum[2][qrow][c0 + j] + Osum[3][qrow][c0 + j];
    size_t base = (((size_t)(b * 64 + qt) * 2 + s) * 16 + qrow) * 64 + c0;
    *(float4*)(NUM + base)     = (float4){n8[0], n8[1], n8[2], n8[3]};
    *(float4*)(NUM + base + 4) = (float4){n8[4], n8[5], n8[6], n8[7]};
    if (c0 == 0)
      DEN[((size_t)(b * 64 + qt) * 2 + s) * 16 + qrow] =
          Dsum[0][qrow] + Dsum[1][qrow] + Dsum[2][qrow] + Dsum[3][qrow];
  }
}

// ---------------- spatial combine: sum 2 partials, divide, +residual -------
__global__ __launch_bounds__(256) void spat_fin(char* __restrict__ ws)
{
  const float* NUM = (const float*)(ws + O_NUM);
  const float* DEN = (const float*)(ws + O_DEN);
  const unsigned short* QT = (const unsigned short*)(ws + O_QT);
  unsigned short* Xs = (unsigned short*)(ws + O_XS);

  const unsigned i = blockIdx.x * 256u + threadIdx.x;   // 65536
  const int c0 = (i & 7) * 8;
  const unsigned row = i >> 3;                          // [0, 8192)
  const int b = row >> 10, p = row & 1023;
  const int qt = p >> 4, r16 = p & 15;
  size_t nb = (((size_t)(b * 64 + qt) * 2) * 16 + r16) * 64 + c0;
  float4 x0 = *(const float4*)(NUM + nb);
  float4 x1 = *(const float4*)(NUM + nb + 4);
  float4 y0 = *(const float4*)(NUM + nb + 1024);        // s=1: +16*64
  float4 y1 = *(const float4*)(NUM + nb + 1028);
  size_t di = ((size_t)(b * 64 + qt) * 2) * 16 + r16;
  float rd = 1.0f / (DEN[di] + DEN[di + 16]);
  float n8[8] = {x0.x + y0.x, x0.y + y0.y, x0.z + y0.z, x0.w + y0.w,
                 x1.x + y1.x, x1.y + y1.y, x1.z + y1.z, x1.w + y1.w};
  size_t ob = (size_t)row * 64 + c0;
  short8 qv = *(const short8*)(QT + ob);
  short8 o8;
#pragma unroll
  for (int j = 0; j < 8; ++j)
    o8[j] = (short)f2bf(n8[j] * rd + bf2f((unsigned short)qv[j]));
  *(short8*)(Xs + ob) = o8;
}

// ---------------- channel S partials (k-split, no atomics) -----------------
// grid 128 = (b:8) x (colT:4 of 128) x (kt:4 of 256). Split-bf16 QK, q split
// hi/lo on the fly from f32.
__global__ __launch_bounds__(256) void chan_S(const float* __restrict__ q,
                                              char* __restrict__ ws)
{
  const unsigned short* kh = (const unsigned short*)(ws + O_KCH);
  const unsigned short* kl = (const unsigned short*)(ws + O_KCL);
  float* Sp = (float*)(ws + O_SP);

  const int b = blockIdx.x >> 4;
  const int colT = (blockIdx.x >> 2) & 3;
  const int kt = blockIdx.x & 3;
  const int w = threadIdx.x >> 6, lane = threadIdx.x & 63;
  const int low4 = lane & 15, quad = lane >> 4;

  f4 acc[4][2];
#pragma unroll
  for (int m = 0; m < 4; ++m)
#pragma unroll
    for (int n = 0; n < 2; ++n) acc[m][n] = (f4){0.f, 0.f, 0.f, 0.f};

  for (int it = 0; it < 8; ++it) {
    const int k = kt * 256 + it * 32 + quad * 8;
    short8 ah[4], al[4];
#pragma unroll
    for (int m = 0; m < 4; ++m) {
      const float* qp = q + ((size_t)(b * 64 + m * 16 + low4)) * 1024 + k;
      float4 u0 = *(const float4*)qp;
      float4 u1 = *(const float4*)(qp + 4);
      float vv[8] = {u0.x, u0.y, u0.z, u0.w, u1.x, u1.y, u1.z, u1.w};
#pragma unroll
      for (int j = 0; j < 8; ++j) {
        float sv = vv[j] * LOG2E;
        unsigned short hi = f2bf(sv);
        ah[m][j] = (short)hi;
        al[m][j] = (short)f2bf(sv - bf2f(hi));
      }
    }
#pragma unroll
    for (int n = 0; n < 2; ++n) {
      const int col = colT * 128 + (w * 2 + n) * 16 + low4;
      size_t ko = ((size_t)(b * 512 + col)) * 1024 + k;
      short8 bh = *(const short8*)(kh + ko);
      short8 bl = *(const short8*)(kl + ko);
#pragma unroll
      for (int m = 0; m < 4; ++m) {
        acc[m][n] = MFMA16(ah[m], bh, acc[m][n]);
        acc[m][n] = MFMA16(al[m], bh, acc[m][n]);
        acc[m][n] = MFMA16(ah[m], bl, acc[m][n]);
      }
    }
  }
#pragma unroll
  for (int m = 0; m < 4; ++m)
#pragma unroll
    for (int n = 0; n < 2; ++n)
#pragma unroll
      for (int r = 0; r < 4; ++r) {
        const int row = m * 16 + quad * 4 + r;
        const int col = colT * 128 + (w * 2 + n) * 16 + low4;
        Sp[(((size_t)kt * 8 + b) * 64 + row) * 512 + col] = acc[m][n][r];
      }
}

// ---------------- channel softmax: sum 4 partials, max-sub, exp2, P --------
// grid 32 = (b:8) x (rt:4 of 16 rows); 16 lanes per row.
__global__ __launch_bounds__(256) void chan_soft(char* __restrict__ ws)
{
  const float* Sp = (const float*)(ws + O_SP);
  unsigned short* P = (unsigned short*)(ws + O_PCH);
  const int b = blockIdx.x >> 2, rt = blockIdx.x & 3;
  const int row = rt * 16 + (threadIdx.x >> 4), tc = threadIdx.x & 15;

  float sv[32];
  float mx = -1e30f;
#pragma unroll
  for (int jj = 0; jj < 32; ++jj) {
    const int col = jj * 16 + tc;
    size_t base = ((size_t)b * 64 + row) * 512 + col;
    float v = Sp[base] + Sp[base + 262144] + Sp[base + 524288] + Sp[base + 786432];
    sv[jj] = v;
    mx = fmaxf(mx, v);
  }
#pragma unroll
  for (int o = 1; o < 16; o <<= 1) mx = fmaxf(mx, __shfl_xor(mx, o, 64));
  float sum = 0.f;
#pragma unroll
  for (int jj = 0; jj < 32; ++jj) {
    float e = exp2fast(sv[jj] - mx);
    sv[jj] = e;
    sum += e;
  }
#pragma unroll
  for (int o = 1; o < 16; o <<= 1) sum += __shfl_xor(sum, o, 64);
  const float rs = 1.0f / sum;
#pragma unroll
  for (int jj = 0; jj < 32; ++jj)
    P[((size_t)b * 64 + row) * 512 + jj * 16 + tc] = f2bf(sv[jj] * rs);
}

// ---------------- channel PV + residual ------------------------------------
// grid 128 = (b:8) x (pt:16 of 64 px); waves take 16 px each.
__global__ __launch_bounds__(256) void chan_B(char* __restrict__ ws)
{
  const unsigned short* P = (const unsigned short*)(ws + O_PCH);
  const unsigned short* Vct = (const unsigned short*)(ws + O_VCT);
  const unsigned short* QT = (const unsigned short*)(ws + O_QT);
  unsigned short* Xc = (unsigned short*)(ws + O_XC);

  const int b = blockIdx.x >> 4, pt = blockIdx.x & 15;
  const int w = threadIdx.x >> 6, lane = threadIdx.x & 63;
  const int low4 = lane & 15, quad = lane >> 4;
  const int p = pt * 64 + w * 16 + low4;

  f4 acc[4];
#pragma unroll
  for (int m = 0; m < 4; ++m) acc[m] = (f4){0.f, 0.f, 0.f, 0.f};

  for (int ks = 0; ks < 16; ++ks) {
    short8 vb = *(const short8*)(Vct + ((size_t)(b * 1024 + p)) * 512 + ks * 32 + quad * 8);
#pragma unroll
    for (int m = 0; m < 4; ++m) {
      short8 a = *(const short8*)(P + ((size_t)(b * 64 + m * 16 + low4)) * 512 + ks * 32 + quad * 8);
      acc[m] = MFMA16(a, vb, acc[m]);
    }
  }
#pragma unroll
  for (int m = 0; m < 4; ++m)
#pragma unroll
    for (int r = 0; r < 4; ++r) {
      const int c = m * 16 + quad * 4 + r;
      size_t o = ((size_t)(b * 1024 + p)) * 64 + c;
      Xc[o] = f2bf(acc[m][r] + bf2f(QT[o]));
    }
}

// ---------------- conv 5x5 + bias + LN stats (8 waves, offset halves) ------
// grid 256 = (s:2) x (b:8) x (pt:16 of 64 px); 512 threads.
// wave = (half: off 0..12 vs 13..24) x (wsub: 16-px subtile). half1 -> LDS,
// half0 adds, biases, stores Yt, accumulates LN stats.
__global__ __launch_bounds__(512) void conv5(char* __restrict__ ws,
                                             const float* __restrict__ sb1,
                                             const float* __restrict__ cb1)
{
  const int id = blockIdx.x;
  const int s = id >> 7, b = (id >> 4) & 7, pt = id & 15;
  const int w = threadIdx.x >> 6, lane = threadIdx.x & 63;
  const int low4 = lane & 15, quad = lane >> 4;
  const int wsub = w & 3, half = w >> 2;

  const unsigned short* X = (const unsigned short*)(ws + (s ? O_XC : O_XS));
  const unsigned short* W1t = (const unsigned short*)(ws + O_W1T);
  unsigned short* Yt = (unsigned short*)(ws + O_YT);
  float* stats = (float*)(ws + O_STATS);
  const float* b1p = s ? cb1 : sb1;

  __shared__ float Hbuf[4][16][65];      // 16.6KB
  __shared__ float red[2][4];

  const int p = pt * 64 + wsub * 16 + low4;
  const int y0 = p >> 5, x0 = p & 31;

  f4 acc[4];
#pragma unroll
  for (int m = 0; m < 4; ++m) acc[m] = (f4){0.f, 0.f, 0.f, 0.f};

  const int o0 = half ? 13 : 0, o1 = half ? 25 : 13;
  for (int off = o0; off < o1; ++off) {
    const int dy = off / 5 - 2, dx = off % 5 - 2;
    const int ys = y0 + dy, xs = x0 + dx;
    const bool valid = ((unsigned)ys < 32u) & ((unsigned)xs < 32u);
    const int psrc = valid ? (p + dy * 32 + dx) : p;
    const unsigned short* xp = X + ((size_t)(b * 1024 + psrc)) * 64;
    const unsigned short* wp = W1t + ((size_t)((s * 25 + off) * 64)) * 64;
#pragma unroll
    for (int ks = 0; ks < 2; ++ks) {
      short8 bv = *(const short8*)(xp + ks * 32 + quad * 8);
      if (!valid) bv = (short8)0;
#pragma unroll
      for (int m = 0; m < 4; ++m) {
        short8 av = *(const short8*)(wp + (m * 16 + low4) * 64 + ks * 32 + quad * 8);
        acc[m] = MFMA16(av, bv, acc[m]);
      }
    }
  }

  if (half) {
#pragma unroll
    for (int m = 0; m < 4; ++m)
#pragma unroll
      for (int r = 0; r < 4; ++r)
        Hbuf[wsub][low4][m * 16 + quad * 4 + r] = acc[m][r];
  }
  __syncthreads();
  if (!half) {
    float ls = 0.f, ls2 = 0.f;
#pragma unroll
    for (int m = 0; m < 4; ++m)
#pragma unroll
      for (int r = 0; r < 4; ++r) {
        const int co = m * 16 + quad * 4 + r;
        float y = acc[m][r] + Hbuf[wsub][low4][co] + b1p[co];
        Yt[((size_t)((s * 8 + b) * 1024 + p)) * 64 + co] = f2bf(y);
        ls += y; ls2 += y * y;
      }
#pragma unroll
    for (int o = 1; o < 64; o <<= 1) {
      ls += __shfl_xor(ls, o, 64);
      ls2 += __shfl_xor(ls2, o, 64);
    }
    if (lane == 0) { red[0][wsub] = ls; red[1][wsub] = ls2; }
  }
  __syncthreads();
  if (threadIdx.x == 0) {
    atomicAdd(&stats[(s * 8 + b) * 2 + 0], red[0][0] + red[0][1] + red[0][2] + red[0][3]);
    atomicAdd(&stats[(s * 8 + b) * 2 + 1], red[1][0] + red[1][1] + red[1][2] + red[1][3]);
  }
}

// ---------------- LN + ReLU + 1x1 conv epilogue ----------------------------
// grid 256 = (s:2) x (b:8) x (pt:16 of 64 px); ln params gathered f32 (L2).
__global__ __launch_bounds__(256) void finalk(char* __restrict__ ws,
                                              const float* __restrict__ slnw,
                                              const float* __restrict__ slnb,
                                              const float* __restrict__ clnw,
                                              const float* __restrict__ clnb,
                                              const float* __restrict__ sb2,
                                              const float* __restrict__ cb2,
                                              float* __restrict__ out)
{
  const int id = blockIdx.x;
  const int s = id >> 7, b = (id >> 4) & 7, pt = id & 15;
  const int w = threadIdx.x >> 6, lane = threadIdx.x & 63;
  const int low4 = lane & 15, quad = lane >> 4;
  const int p2 = pt * 64 + w * 16 + low4;

  const unsigned short* Yt = (const unsigned short*)(ws + O_YT);
  const unsigned short* W2b = (const unsigned short*)(ws + O_W2B);
  const float* stats = (const float*)(ws + O_STATS);
  const float* lw = s ? clnw : slnw;
  const float* lb = s ? clnb : slnb;
  const float* b2p = s ? cb2 : sb2;

  const float inv = 1.0f / 65536.0f;
  const float mu = stats[(s * 8 + b) * 2 + 0] * inv;
  const float ms = stats[(s * 8 + b) * 2 + 1] * inv;
  const float rsig = rsqrtf(ms - mu * mu + 1e-5f);

  f4 acc[8];
#pragma unroll
  for (int m = 0; m < 8; ++m) acc[m] = (f4){0.f, 0.f, 0.f, 0.f};

#pragma unroll
  for (int ks = 0; ks < 2; ++ks) {
    size_t yo = ((size_t)((s * 8 + b) * 1024 + p2)) * 64 + ks * 32 + quad * 8;
    short8 yv = *(const short8*)(Yt + yo);
    short8 zv;
#pragma unroll
    for (int j = 0; j < 8; ++j) {
      const int c = ks * 32 + quad * 8 + j;
      float z = (bf2f((unsigned short)yv[j]) - mu) * rsig * lw[c * 1024 + p2] + lb[c * 1024 + p2];
      zv[j] = (short)f2bf(fmaxf(z, 0.f));
    }
#pragma unroll
    for (int m = 0; m < 8; ++m) {
      short8 a = *(const short8*)(W2b + ((size_t)(s * 128 + m * 16 + low4)) * 64 + ks * 32 + quad * 8);
      acc[m] = MFMA16(a, zv, acc[m]);
    }
  }
#pragma unroll
  for (int m = 0; m < 8; ++m)
#pragma unroll
    for (int r = 0; r < 4; ++r) {
      const int nh = m * 16 + quad * 4 + r;
      out[((size_t)((s * 8 + b) * 128 + nh)) * 1024 + p2] = acc[m][r] + b2p[nh];
    }
}

extern "C" void kernel_launch(void* const* d_in, const int* in_sizes, int n_in,
                              void* d_out, int out_size, void* d_ws, size_t ws_size,
                              hipStream_t stream)
{
  const float* q    = (const float*)d_in[0];
  const float* keys = (const float*)d_in[1];
  const float* vals = (const float*)d_in[2];
  const float* sw1  = (const float*)d_in[3];
  const float* sb1  = (const float*)d_in[4];
  const float* slnw = (const float*)d_in[5];
  const float* slnb = (const float*)d_in[6];
  const float* sw2  = (const float*)d_in[7];
  const float* sb2  = (const float*)d_in[8];
  const float* cw1  = (const float*)d_in[9];
  const float* cb1  = (const float*)d_in[10];
  const float* clnw = (const float*)d_in[11];
  const float* clnb = (const float*)d_in[12];
  const float* cw2  = (const float*)d_in[13];
  const float* cb2  = (const float*)d_in[14];
  char* ws = (char*)d_ws;

  hipMemsetAsync(ws + O_STATS, 0, 256, stream);
  prep_misc<<<864, 256, 0, stream>>>(sw1, sw2, cw1, cw2, ws);
  prep_tr<<<2176, 256, 0, stream>>>(q, keys, vals, ws);
  spat_attn<<<1024, 256, 0, stream>>>(ws);
  spat_fin<<<256, 256, 0, stream>>>(ws);
  chan_S<<<128, 256, 0, stream>>>(q, ws);
  chan_soft<<<32, 256, 0, stream>>>(ws);
  chan_B<<<128, 256, 0, stream>>>(ws);
  conv5<<<256, 512, 0, stream>>>(ws, sb1, cb1);
  finalk<<<256, 256, 0, stream>>>(ws, slnw, slnb, clnw, clnb, sb2, cb2, (float*)d_out);
}